// Round 3
// baseline (88.276 us; speedup 1.0000x reference)
//
#include <hip/hip_runtime.h>

// LIF recurrence: mem = 0.9*mem + x; spike = (mem >= 1); record spike & mem;
// mem -= spike. T=20 steps, elementwise-independent -> one thread per float4.
//
// Output layout (concatenated flat, return order):
//   out[0          .. T*N-1]   = spike_trains  [T][64][8192]
//   out[T*N        .. 2*T*N-1] = membrane_pot  [T][64][8192]
//
// R5 change: de-interleave the two output streams in time.
//   Evidence: R3 (4x occupancy, same pattern) = zero delta -> downstream,
//   pattern-dependent BW limit. Kernel sustains ~2.6 TB/s while the
//   harness's single-stream fill hits 6.15 TB/s on the same buffer (0.42x
//   ~= HBM row-thrash band). Old loop alternated stores to two slices
//   84 MB apart every iteration; 84 MB is channel-map-aligned, so both
//   streams hit the same banks on different rows -> activate/precharge
//   per access.
//   Now: phase 1 stores spikes in-loop and buffers the 20 recorded mem
//   vectors in registers (20 x v4f = 80 VGPR, statically indexed ->
//   register-allocated); phase 2 stores all 20 mem slices. Each phase is a
//   single pure write stream. Store ORDER changes only -- the value-
//   producing op sequence is identical to R4 (absmax=0.0 measured), so
//   numerics are bit-identical by construction. No recompute (R3 lesson).
//
// Numerics: forced mul-then-add rounding (__fmul_rn/__fadd_rn), no FMA
// contraction -- matches numpy fp32 exactly.

#define TSTEPS 20

typedef float v4f __attribute__((ext_vector_type(4)));

__global__ __launch_bounds__(256) void
TemporalEncoding_57672820850797_kernel(const v4f* __restrict__ x,
                                       float* __restrict__ out, int n4) {
    int i = blockIdx.x * blockDim.x + threadIdx.x;  // float4 index
    if (i >= n4) return;

    const v4f xv = x[i];
    v4f* __restrict__ spikes = reinterpret_cast<v4f*>(out) + i;
    v4f* __restrict__ mems   = reinterpret_cast<v4f*>(out) + (size_t)TSTEPS * n4 + i;

    float m0 = 0.f, m1 = 0.f, m2 = 0.f, m3 = 0.f;
    v4f membuf[TSTEPS];  // fully unrolled static indexing -> registers

    // ---- Phase 1: recurrence + spike stores (single stream) ----
#pragma unroll
    for (int t = 0; t < TSTEPS; ++t) {
        // mem = 0.9*mem + x, with separate rounding steps (no FMA contraction)
        m0 = __fadd_rn(__fmul_rn(0.9f, m0), xv.x);
        m1 = __fadd_rn(__fmul_rn(0.9f, m1), xv.y);
        m2 = __fadd_rn(__fmul_rn(0.9f, m2), xv.z);
        m3 = __fadd_rn(__fmul_rn(0.9f, m3), xv.w);

        float s0 = (m0 >= 1.0f) ? 1.0f : 0.0f;
        float s1 = (m1 >= 1.0f) ? 1.0f : 0.0f;
        float s2 = (m2 >= 1.0f) ? 1.0f : 0.0f;
        float s3 = (m3 >= 1.0f) ? 1.0f : 0.0f;

        v4f sv; sv.x = s0; sv.y = s1; sv.z = s2; sv.w = s3;
        *spikes = sv;
        spikes += n4;

        v4f mv; mv.x = m0; mv.y = m1; mv.z = m2; mv.w = m3;
        membuf[t] = mv;  // defer the second stream

        // reset: mem -= spike*thr  (thr = 1.0, exact subtraction)
        m0 -= s0;
        m1 -= s1;
        m2 -= s2;
        m3 -= s3;
    }

    // Pin the phase boundary: align waves in the block and stop the
    // scheduler from interleaving phase-2 stores into phase 1.
    __syncthreads();
    __builtin_amdgcn_sched_barrier(0);

    // ---- Phase 2: membrane-potential stores (single stream) ----
#pragma unroll
    for (int t = 0; t < TSTEPS; ++t) {
        mems[(size_t)t * n4] = membuf[t];
    }
}

extern "C" void kernel_launch(void* const* d_in, const int* in_sizes, int n_in,
                              void* d_out, int out_size, void* d_ws, size_t ws_size,
                              hipStream_t stream) {
    const float* x = (const float*)d_in[0];
    float* out = (float*)d_out;
    const int n = in_sizes[0];       // 64*8192 = 524288
    const int n4 = n / 4;            // 131072 float4 lanes
    const int block = 256;
    const int grid = (n4 + block - 1) / block;  // 512 blocks
    TemporalEncoding_57672820850797_kernel<<<grid, block, 0, stream>>>(
        (const v4f*)x, out, n4);
}